// Round 4
// baseline (25393.932 us; speedup 1.0000x reference)
//
#include <hip/hip_runtime.h>

typedef unsigned short u16;
typedef unsigned int   u32;
typedef unsigned long long u64;
typedef signed char    i8;
typedef __attribute__((ext_vector_type(4))) int  i32x4;
typedef __attribute__((ext_vector_type(2))) long i64x2;

// ---------------- problem constants ----------------
#define NSTEP 512

// ---------------- workspace layout (bytes) ----------------
#define OFF_QX8   0ull
#define SZ_QX8    (32768ull*512)            // x quantized, int8
#define OFF_QWT8  (OFF_QX8 + SZ_QX8)
#define SZ_QT8    (1536ull*512)             // W^T / R^T quantized, int8
#define OFF_QRT8  (OFF_QWT8 + SZ_QT8)
#define OFF_QWX   (OFF_QRT8 + SZ_QT8)
#define SZ_QWX    (32768ull*1536)           // Wx quantized, int8
#define OFF_QBX   (OFF_QWX + SZ_QWX)        // 1536 int
#define OFF_QBR   (OFF_QBX + 6144)          // 1536 int
#define OFF_LUT   (OFF_QBR + 6144)          // 256 int sigmoid + 256 int tanh
#define OFF_RINGF (OFF_LUT + 2048)          // fast ring (L2 domain)
#define RING_WORDS (2*4*4096)               // 2 slots x 4 bg x 4096 u32
#define SZ_RING   (RING_WORDS*4ull)
#define OFF_RINGS (OFF_RINGF + SZ_RING)     // slow ring (LLC domain)
#define OFF_XCC   (OFF_RINGS + SZ_RING)     // 64-word xcc table
#define WS_NEED   (OFF_XCC + 256)

// ---------------- helpers ----------------
__device__ __forceinline__ int iclip8(int v){ return v < -128 ? -128 : (v > 127 ? 127 : v); }

// round-half-even of (v / 2^k) for integer v (matches jnp.round on exact values)
__device__ __forceinline__ int rhe(int v, int k){
  int b = v >> k;
  int r = v & ((1 << k) - 1);
  int half = 1 << (k - 1);
  return b + ((r > half) || (r == half && (b & 1)));
}

__device__ __forceinline__ int qi8(float x, float s){
  float q = rintf(x * s);
  q = fminf(fmaxf(q, -128.f), 127.f);
  return (int)q;
}

// MFMA i8 wrapper: tolerate either i32x4- or i64x2-typed builtin signature.
template<typename V>
__device__ __forceinline__ auto mfma_i8_try(V a, V b, i32x4 c, int)
  -> decltype(__builtin_amdgcn_mfma_i32_16x16x64_i8(a, b, c, 0, 0, 0)) {
  return __builtin_amdgcn_mfma_i32_16x16x64_i8(a, b, c, 0, 0, 0);
}
template<typename V>
__device__ __forceinline__ i32x4 mfma_i8_try(V a, V b, i32x4 c, long) {
  return __builtin_amdgcn_mfma_i32_16x16x64_i8(
      __builtin_bit_cast(i64x2, a), __builtin_bit_cast(i64x2, b), c, 0, 0, 0);
}
__device__ __forceinline__ i32x4 mfma_i8(i32x4 a, i32x4 b, i32x4 c){
  return mfma_i8_try(a, b, c, 0);
}

// scoped stores/loads
__device__ __forceinline__ void st_sc0(u32* p, u32 v){        // L2 domain (bypass L1)
  asm volatile("global_store_dword %0, %1, off sc0" :: "v"((u64)p), "v"(v) : "memory");
}
__device__ __forceinline__ void st_sc01(u32* p, u32 v){       // LLC domain
  asm volatile("global_store_dword %0, %1, off sc0 sc1" :: "v"((u64)p), "v"(v) : "memory");
}
__device__ __forceinline__ u32 ld32_sc01(const u32* p){
  u32 r;
  asm volatile("global_load_dword %0, %1, off sc0 sc1\n\ts_waitcnt vmcnt(0)"
               : "=v"(r) : "v"((u64)p) : "memory");
  return r;
}
__device__ __forceinline__ void llc_zero16(u32* p){
  i32x4 z = {0,0,0,0};
  asm volatile("global_store_dwordx4 %0, %1, off sc0 sc1" :: "v"((u64)p), "v"(z) : "memory");
}

// ---------------- phase -1: flush stale dirty L2 lines (prev replay) --------
__global__ void k_flush(u32* sink){
  __threadfence_system();                 // wbL2 + inv on this XCD
  if ((int)blockIdx.x == -1) sink[0] = 1; // never taken; keeps kernel non-trivial
}

// ---------------- phase 0: quantization / tables ----------------
__global__ void k0a_qx(const float* __restrict__ x, u32* __restrict__ qx8, int n4){
  int i = blockIdx.x * blockDim.x + threadIdx.x;
  int st = gridDim.x * blockDim.x;
  for (; i < n4; i += st) {
    float4 v = ((const float4*)x)[i];
    u32 b0 = (u32)(qi8(v.x, 16.f) & 0xFF);
    u32 b1 = (u32)(qi8(v.y, 16.f) & 0xFF);
    u32 b2 = (u32)(qi8(v.z, 16.f) & 0xFF);
    u32 b3 = (u32)(qi8(v.w, 16.f) & 0xFF);
    qx8[i] = b0 | (b1 << 8) | (b2 << 16) | (b3 << 24);
  }
}

__global__ void k0b_qwr(const float* __restrict__ W, const float* __restrict__ Rm,
                        i8* __restrict__ qwT8, i8* __restrict__ qrT8){
  int idx = blockIdx.x * 256 + threadIdx.x;       // 0 .. 2*786432-1
  if (idx >= 2*786432) return;
  int m = idx >= 786432;
  int rem = idx - m * 786432;                     // = k*1536 + n (coalesced read)
  int k = rem / 1536;
  int n = rem - k * 1536;
  const float* s = m ? Rm : W;
  i8* d = m ? qrT8 : qwT8;
  d[n*512 + k] = (i8)qi8(s[rem], 1024.f);
}

__global__ void k0c_misc(const float* __restrict__ bx, const float* __restrict__ br,
                         int* __restrict__ qbx, int* __restrict__ qbr,
                         int* __restrict__ lut, u32* __restrict__ ringF,
                         u32* __restrict__ ringS, u32* __restrict__ xcctab){
  int i = blockIdx.x * 256 + threadIdx.x;         // 4096 threads
  if (i < 1536) {
    qbx[i] = iclip8((int)rintf(bx[i] * 256.f));
    qbr[i] = iclip8((int)rintf(br[i] * 256.f));
  }
  if (i < 256) {
    double v = (i - 128) * 0.125;                 // all possible pre-activations
    float sg = (float)(1.0 / (1.0 + exp(-v)));
    int qs = (int)rintf(sg * 256.f);
    lut[i] = qs < 0 ? 0 : (qs > 255 ? 255 : qs);
    float th = (float)tanh(v);
    lut[256 + i] = iclip8((int)rintf(th * 128.f));
  }
  // zero rings + xcc table EVERY launch (LLC domain; tags are >=1)
  llc_zero16(ringF + i*8);
  llc_zero16(ringF + i*8 + 4);
  llc_zero16(ringS + i*8);
  llc_zero16(ringS + i*8 + 4);
  if (i < 64) st_sc01(xcctab + i, 0u);
}

// ---------------- phase 1: Wx = fq(xq @ Wq, 4), stored int8 ----------------
__global__ __launch_bounds__(256) void k1_gemm_wx(const i8* __restrict__ qx8,
                                                  const i8* __restrict__ qwT8,
                                                  i8* __restrict__ qwx){
  __shared__ i8 xs[128][80];
  __shared__ i8 ws[128][80];
  int bid = blockIdx.x;
  int n0 = (bid % 12) * 128;
  int m0 = (bid / 12) * 128;
  int tid = threadIdx.x;
  int lane = tid & 63, wid = tid >> 6;
  int wm = wid >> 1, wn = wid & 1;
  int g = lane >> 4, l15 = lane & 15;

  i32x4 acc[4][4] = {};
  for (int kc = 0; kc < 512; kc += 64) {
    __syncthreads();
#pragma unroll
    for (int p = 0; p < 4; p++) {
      int idx = p*256 + tid;
      int mat = idx >> 9;
      int i2  = idx & 511;
      int r   = i2 >> 2;
      int c16 = (i2 & 3) << 4;
      const i8* src = mat ? qwT8 : qx8;
      int base = mat ? n0 : m0;
      uint4 val = *(const uint4*)&src[(size_t)(base + r)*512 + kc + c16];
      if (mat) *(uint4*)&ws[r][c16] = val;
      else     *(uint4*)&xs[r][c16] = val;
    }
    __syncthreads();
    i32x4 a[4], b[4];
#pragma unroll
    for (int t = 0; t < 4; t++) {
      a[t] = *(const i32x4*)&xs[wm*64 + t*16 + l15][g*16];
      b[t] = *(const i32x4*)&ws[wn*64 + t*16 + l15][g*16];
    }
#pragma unroll
    for (int i = 0; i < 4; i++)
#pragma unroll
      for (int j = 0; j < 4; j++)
        acc[i][j] = mfma_i8(a[i], b[j], acc[i][j]);
  }
#pragma unroll
  for (int i = 0; i < 4; i++)
#pragma unroll
    for (int j = 0; j < 4; j++)
#pragma unroll
      for (int r = 0; r < 4; r++) {
        int q = iclip8(rhe(acc[i][j][r], 10));
        int row = m0 + wm*64 + i*16 + g*4 + r;
        int col = n0 + wn*64 + j*16 + l15;
        qwx[(size_t)row * 1536 + col] = (i8)q;
      }
}

// ---------------- phase 2: 512-step recurrence ----------------
// 128 WGs launched, 64 active: bg = bid&7 (<4), cg = bid>>3. Under round-robin
// bid%8 -> XCD, each bg's 16 WGs share one XCD -> exchange h through that L2
// (sc0). Startup XCC handshake decides fast/slow; producers dual-store so the
// LLC ring is always a valid fallback (correctness never depends on placement).
__global__ __launch_bounds__(256, 1) void k2_gru(const float* __restrict__ h0,
                                                 const i8*  __restrict__ qwx,
                                                 const i8*  __restrict__ qrT8,
                                                 const int* __restrict__ qbx,
                                                 const int* __restrict__ qbr,
                                                 const int* __restrict__ lut,
                                                 u32* __restrict__ ringF,
                                                 u32* __restrict__ ringS,
                                                 u32* __restrict__ xcctab,
                                                 float* __restrict__ out){
  const int bid = blockIdx.x;
  const int bg  = bid & 7;
  if (bg >= 4) return;
  const int cg  = bid >> 3;                       // 0..15
  const int tid = threadIdx.x;
  const int lane = tid & 63, wid = tid >> 6;      // wave = K-slice of 128
  const int g = lane >> 4, l15 = lane & 15;

  __shared__ int l_sig[256], l_th[256];
  __shared__ int red[2][4][16][100];              // [parity][wave][row][96+pad]
  __shared__ int s_fast;

  if (tid < 256) { l_sig[tid] = lut[tid]; l_th[tid] = lut[256 + tid]; }

  int xcc;
  asm volatile("s_getreg_b32 %0, hwreg(HW_REG_XCC_ID)" : "=s"(xcc));
  if (tid == 0) st_sc01(xcctab + bg*16 + cg, 0x100u | ((u32)xcc & 0xFFu));

  // ---- R fragments (B operand), int8, resident: 6 n-tiles x 2 k-chunks
  i32x4 rf[6][2];
#pragma unroll
  for (int n = 0; n < 6; n++) {
    int colR = (n >> 1)*512 + cg*32 + (n & 1)*16 + l15;
#pragma unroll
    for (int m = 0; m < 2; m++)
      rf[n][m] = *(const i32x4*)&qrT8[(size_t)colR*512 + wid*128 + m*64 + g*16];
  }

  // ---- own h state: 2 elements per thread (row = tid>>4, cols c0,c0+1)
  const int row = tid >> 4;
  const int c0  = (tid & 15) << 1;
  int bxz[2], bxr[2], bxn[2], brz[2], brr[2], brn[2];
#pragma unroll
  for (int cc = 0; cc < 2; cc++) {
    int col = cg*32 + c0 + cc;
    bxz[cc] = qbx[col]; bxr[cc] = qbx[512 + col]; bxn[cc] = qbx[1024 + col];
    brz[cc] = qbr[col]; brr[cc] = qbr[512 + col]; brn[cc] = qbr[1024 + col];
  }
  int qh[2];
  {
    float2 h2 = *(const float2*)&h0[(size_t)(bg*16 + row)*512 + cg*32 + c0];
    qh[0] = qi8(h2.x, 128.f); qh[1] = qi8(h2.y, 128.f);
  }

  // producer word index: k = cg*32+c0 -> (w,m,g,j); word packs 2 int8 + tag16
  const int kprod = cg*32 + c0;
  const int pwidx = (((kprod >> 7)*4 + ((kprod >> 4) & 3))*16 + row)*16
                  + (((kprod >> 6) & 1) << 3) + ((kprod >> 1) & 7);

  // ---- startup handshake: are all 16 WGs of this bg on my XCD?
  if (wid == 0) {
    int match = 1;
    if (lane < 16) {
      u32 v;
      do { v = ld32_sc01(xcctab + bg*16 + lane); } while (!(v & 0x100u));
      match = ((int)(v & 0xFFu) == (xcc & 0xFF));
    }
    unsigned long long b = __ballot(match);
    if (lane == 0) s_fast = (b == ~0ull) ? 1 : 0;
  }
  __syncthreads();
  int use_fast = s_fast;

  // ---- publish h(0): slot 0, tag 1, both rings
  {
    u32 wv = (u32)(qh[0] & 0xFF) | ((u32)(qh[1] & 0xFF) << 8) | (1u << 16);
    st_sc0 (ringF + bg*4096 + pwidx, wv);
    st_sc01(ringS + bg*4096 + pwidx, wv);
  }

  // ---- Wx pre-load for t=0 (one step ahead thereafter)
  u32 wzw, wrw, wgw;
  {
    const i8* wxp = qwx + (size_t)(bg*16 + row)*1536 + cg*32;
    wzw = *(const u16*)(wxp + c0);
    wrw = *(const u16*)(wxp + 512 + c0);
    wgw = *(const u16*)(wxp + 1024 + c0);
  }

  const u64 laneoff = (u64)((wid*64 + g*16 + l15) * 64);  // bytes into image

  for (int t = 0; t < NSTEP; t++) {
    const u32 want  = (u32)(t + 1);
    const u32 want2 = want | (want << 16);
    const u64 slotoff = (u64)(((t & 1)*4 + bg) * 16384);
    const u64 aF = (u64)ringF + slotoff + laneoff;
    const u64 aS = (u64)ringS + slotoff + laneoff;
    uint4 P0, P1, P2, P3;
    int rounds = 0;
    for (;;) {
      if (use_fast) {
        asm volatile(
          "global_load_dwordx4 %0, %4, off sc0\n\t"
          "global_load_dwordx4 %1, %4, off offset:16 sc0\n\t"
          "global_load_dwordx4 %2, %4, off offset:32 sc0\n\t"
          "global_load_dwordx4 %3, %4, off offset:48 sc0\n\t"
          "s_waitcnt vmcnt(0)"
          : "=&v"(P0), "=&v"(P1), "=&v"(P2), "=&v"(P3) : "v"(aF) : "memory");
      } else {
        asm volatile(
          "global_load_dwordx4 %0, %4, off sc0 sc1\n\t"
          "global_load_dwordx4 %1, %4, off offset:16 sc0 sc1\n\t"
          "global_load_dwordx4 %2, %4, off offset:32 sc0 sc1\n\t"
          "global_load_dwordx4 %3, %4, off offset:48 sc0 sc1\n\t"
          "s_waitcnt vmcnt(0)"
          : "=&v"(P0), "=&v"(P1), "=&v"(P2), "=&v"(P3) : "v"(aS) : "memory");
      }
      u32 diff;
      diff  = __builtin_amdgcn_perm(P0.y, P0.x, 0x07060302u) ^ want2;
      diff |= __builtin_amdgcn_perm(P0.w, P0.z, 0x07060302u) ^ want2;
      diff |= __builtin_amdgcn_perm(P1.y, P1.x, 0x07060302u) ^ want2;
      diff |= __builtin_amdgcn_perm(P1.w, P1.z, 0x07060302u) ^ want2;
      diff |= __builtin_amdgcn_perm(P2.y, P2.x, 0x07060302u) ^ want2;
      diff |= __builtin_amdgcn_perm(P2.w, P2.z, 0x07060302u) ^ want2;
      diff |= __builtin_amdgcn_perm(P3.y, P3.x, 0x07060302u) ^ want2;
      diff |= __builtin_amdgcn_perm(P3.w, P3.z, 0x07060302u) ^ want2;
      if (diff == 0u) break;
      if (use_fast) { if (++rounds > 4096) { use_fast = 0; rounds = 0; } }
      else if (++rounds > (1 << 24)) break;       // safety valve
      __builtin_amdgcn_s_sleep(1);
    }

    // next-step Wx prefetch (latency hidden under compute; drained by next poll)
    u32 nzw = 0, nrw = 0, ngw = 0;
    if (t < NSTEP - 1) {
      const i8* wxp = qwx + (size_t)(t + 1)*98304 + (size_t)(bg*16 + row)*1536 + cg*32;
      nzw = *(const u16*)(wxp + c0);
      nrw = *(const u16*)(wxp + 512 + c0);
      ngw = *(const u16*)(wxp + 1024 + c0);
    }

    // ---- pack A (strip tags) and run the 12 MFMAs
    i32x4 acc[6] = {};
    {
      i32x4 a0, a1;
      a0.x = (int)__builtin_amdgcn_perm(P0.y, P0.x, 0x05040100u);
      a0.y = (int)__builtin_amdgcn_perm(P0.w, P0.z, 0x05040100u);
      a0.z = (int)__builtin_amdgcn_perm(P1.y, P1.x, 0x05040100u);
      a0.w = (int)__builtin_amdgcn_perm(P1.w, P1.z, 0x05040100u);
      a1.x = (int)__builtin_amdgcn_perm(P2.y, P2.x, 0x05040100u);
      a1.y = (int)__builtin_amdgcn_perm(P2.w, P2.z, 0x05040100u);
      a1.z = (int)__builtin_amdgcn_perm(P3.y, P3.x, 0x05040100u);
      a1.w = (int)__builtin_amdgcn_perm(P3.w, P3.z, 0x05040100u);
#pragma unroll
      for (int n = 0; n < 6; n++) acc[n] = mfma_i8(a0, rf[n][0], acc[n]);
#pragma unroll
      for (int n = 0; n < 6; n++) acc[n] = mfma_i8(a1, rf[n][1], acc[n]);
    }

    // ---- per-wave partials to LDS (parity buffer), ONE barrier per step
    const int par = t & 1;
#pragma unroll
    for (int n = 0; n < 6; n++)
#pragma unroll
      for (int r = 0; r < 4; r++)
        red[par][wid][g*4 + r][n*16 + l15] = acc[n][r];
    __syncthreads();

    // ---- fused reduce + quantize + gates for this thread's 2 columns
    const int* rbase = &red[par][0][row][0];      // slice stride = 1600 words
    int rz[2], rr[2], rg[2];
#pragma unroll
    for (int cc = 0; cc < 2; cc++) {
      int c = c0 + cc;
      int Sz = rbase[c]      + rbase[1600 + c]      + rbase[3200 + c]      + rbase[4800 + c];
      int Sr = rbase[32 + c] + rbase[1632 + c]      + rbase[3232 + c]      + rbase[4832 + c];
      int Sn = rbase[64 + c] + rbase[1664 + c]      + rbase[3264 + c]      + rbase[4864 + c];
      rz[cc] = iclip8(rhe(iclip8(rhe(Sz, 13))*16 + brz[cc], 4));
      rr[cc] = iclip8(rhe(iclip8(rhe(Sr, 13))*16 + brr[cc], 4));
      rg[cc] = iclip8(rhe(iclip8(rhe(Sn, 13))*16 + brn[cc], 4));
    }
#pragma unroll
    for (int cc = 0; cc < 2; cc++) {
      int wz = (int)(i8)((wzw >> (8*cc)) & 0xFF);
      int wr = (int)(i8)((wrw >> (8*cc)) & 0xFF);
      int wg = (int)(i8)((wgw >> (8*cc)) & 0xFF);
      int uz  = l_sig[128 + iclip8(rhe(16*(wz + rz[cc]) + bxz[cc], 5))];
      int ur  = l_sig[128 + iclip8(rhe(16*(wr + rr[cc]) + bxr[cc], 5))];
      int qrh = iclip8(rhe(ur * rg[cc], 8));
      int qg  = l_th[128 + iclip8(rhe(16*(wg + qrh) + bxn[cc], 5))];
      int qold = iclip8(rhe(uz * qh[cc], 8));
      int qnew = iclip8(rhe((256 - uz) * qg, 8));
      qh[cc] = iclip8(qold + qnew);
    }

    // ---- publish h(t+1) FIRST (both rings), then out
    {
      u32 tg = (u32)(t + 2) << 16;
      u32 wv = (u32)(qh[0] & 0xFF) | ((u32)(qh[1] & 0xFF) << 8) | tg;
      u64 po = (u64)((((t + 1) & 1)*4 + bg) * 16384 + pwidx*4);
      st_sc0 ((u32*)((u64)ringF + po), wv);
      st_sc01((u32*)((u64)ringS + po), wv);
    }
    float2 ov;
    ov.x = qh[0] * 0.0078125f; ov.y = qh[1] * 0.0078125f;
    *(float2*)&out[((size_t)t*64 + bg*16 + row)*512 + cg*32 + c0] = ov;

    wzw = nzw; wrw = nrw; wgw = ngw;
  }
}

// ---------------- launch ----------------
extern "C" void kernel_launch(void* const* d_in, const int* in_sizes, int n_in,
                              void* d_out, int out_size, void* d_ws, size_t ws_size,
                              hipStream_t stream) {
  const float* x  = (const float*)d_in[0];
  const float* h0 = (const float*)d_in[1];
  const float* W  = (const float*)d_in[2];
  const float* R  = (const float*)d_in[3];
  const float* bx = (const float*)d_in[4];
  const float* br = (const float*)d_in[5];
  float* out = (float*)d_out;

  if (ws_size < WS_NEED) return;   // insufficient scratch; fail loudly

  char* ws = (char*)d_ws;
  i8*  qx8   = (i8*) (ws + OFF_QX8);
  i8*  qwT8  = (i8*) (ws + OFF_QWT8);
  i8*  qrT8  = (i8*) (ws + OFF_QRT8);
  i8*  qwx   = (i8*) (ws + OFF_QWX);
  int* qbx   = (int*)(ws + OFF_QBX);
  int* qbr   = (int*)(ws + OFF_QBR);
  int* lut   = (int*)(ws + OFF_LUT);
  u32* ringF = (u32*)(ws + OFF_RINGF);
  u32* ringS = (u32*)(ws + OFF_RINGS);
  u32* xcct  = (u32*)(ws + OFF_XCC);

  k_flush <<<64,   64,  0, stream>>>(xcct);
  k0a_qx  <<<2048, 256, 0, stream>>>(x, (u32*)qx8, 32768*512/4);
  k0b_qwr <<<6144, 256, 0, stream>>>(W, R, qwT8, qrT8);
  k0c_misc<<<16,   256, 0, stream>>>(bx, br, qbx, qbr, lut, ringF, ringS, xcct);
  k1_gemm_wx<<<3072, 256, 0, stream>>>(qx8, qwT8, qwx);
  k2_gru  <<<128, 256, 0, stream>>>(h0, qwx, qrT8, qbx, qbr, lut, ringF, ringS, xcct, out);
}

// Round 5
// 1501.657 us; speedup vs baseline: 16.9106x; 16.9106x over previous
//
#include <hip/hip_runtime.h>

typedef unsigned short u16;
typedef unsigned int   u32;
typedef unsigned long long u64;
typedef signed char    i8;
typedef __attribute__((ext_vector_type(4))) int  i32x4;
typedef __attribute__((ext_vector_type(2))) long i64x2;

// ---------------- problem constants ----------------
#define NSTEP 512

// ---------------- workspace layout (bytes) ----------------
#define OFF_QX8   0ull
#define SZ_QX8    (32768ull*512)            // x quantized, int8
#define OFF_QWT8  (OFF_QX8 + SZ_QX8)
#define SZ_QT8    (1536ull*512)             // W^T / R^T quantized, int8
#define OFF_QRT8  (OFF_QWT8 + SZ_QT8)
#define OFF_QWX   (OFF_QRT8 + SZ_QT8)
#define SZ_QWX    (32768ull*1536)           // Wx quantized, int8
#define OFF_QBX   (OFF_QWX + SZ_QWX)        // 1536 int
#define OFF_QBR   (OFF_QBX + 6144)          // 1536 int
#define OFF_LUT   (OFF_QBR + 6144)          // 256 int sigmoid + 256 int tanh
#define OFF_RING  (OFF_LUT + 2048)          // 2 slots x 4 bg x 4096 u32 tagged h-words
#define RING_WORDS (2*4*4096)
#define SZ_RING   (RING_WORDS*4ull)
#define WS_NEED   (OFF_RING + SZ_RING)

// ---------------- helpers ----------------
__device__ __forceinline__ int iclip8(int v){ return v < -128 ? -128 : (v > 127 ? 127 : v); }

// round-half-even of (v / 2^k) for integer v (matches jnp.round on exact values)
__device__ __forceinline__ int rhe(int v, int k){
  int b = v >> k;
  int r = v & ((1 << k) - 1);
  int half = 1 << (k - 1);
  return b + ((r > half) || (r == half && (b & 1)));
}

__device__ __forceinline__ int qi8(float x, float s){
  float q = rintf(x * s);
  q = fminf(fmaxf(q, -128.f), 127.f);
  return (int)q;
}

// MFMA i8 wrapper: tolerate either i32x4- or i64x2-typed builtin signature.
template<typename V>
__device__ __forceinline__ auto mfma_i8_try(V a, V b, i32x4 c, int)
  -> decltype(__builtin_amdgcn_mfma_i32_16x16x64_i8(a, b, c, 0, 0, 0)) {
  return __builtin_amdgcn_mfma_i32_16x16x64_i8(a, b, c, 0, 0, 0);
}
template<typename V>
__device__ __forceinline__ i32x4 mfma_i8_try(V a, V b, i32x4 c, long) {
  return __builtin_amdgcn_mfma_i32_16x16x64_i8(
      __builtin_bit_cast(i64x2, a), __builtin_bit_cast(i64x2, b), c, 0, 0, 0);
}
__device__ __forceinline__ i32x4 mfma_i8(i32x4 a, i32x4 b, i32x4 c){
  return mfma_i8_try(a, b, c, 0);
}

// LLC-coherent (bypass L1+L2) store/zero — the PROVEN exchange fabric (R2)
__device__ __forceinline__ void st_llc(u32* p, u32 v){
  asm volatile("global_store_dword %0, %1, off sc0 sc1" :: "v"((u64)p), "v"(v) : "memory");
}
__device__ __forceinline__ void llc_zero16(u32* p){
  i32x4 z = {0,0,0,0};
  asm volatile("global_store_dwordx4 %0, %1, off sc0 sc1" :: "v"((u64)p), "v"(z) : "memory");
}

// ---------------- phase 0: quantization / tables ----------------
__global__ void k0a_qx(const float* __restrict__ x, u32* __restrict__ qx8, int n4){
  int i = blockIdx.x * blockDim.x + threadIdx.x;
  int st = gridDim.x * blockDim.x;
  for (; i < n4; i += st) {
    float4 v = ((const float4*)x)[i];
    u32 b0 = (u32)(qi8(v.x, 16.f) & 0xFF);
    u32 b1 = (u32)(qi8(v.y, 16.f) & 0xFF);
    u32 b2 = (u32)(qi8(v.z, 16.f) & 0xFF);
    u32 b3 = (u32)(qi8(v.w, 16.f) & 0xFF);
    qx8[i] = b0 | (b1 << 8) | (b2 << 16) | (b3 << 24);
  }
}

__global__ void k0b_qwr(const float* __restrict__ W, const float* __restrict__ Rm,
                        i8* __restrict__ qwT8, i8* __restrict__ qrT8){
  int idx = blockIdx.x * 256 + threadIdx.x;       // 0 .. 2*786432-1
  if (idx >= 2*786432) return;
  int m = idx >= 786432;
  int rem = idx - m * 786432;                     // = k*1536 + n (coalesced read)
  int k = rem / 1536;
  int n = rem - k * 1536;
  const float* s = m ? Rm : W;
  i8* d = m ? qrT8 : qwT8;
  d[n*512 + k] = (i8)qi8(s[rem], 1024.f);
}

__global__ void k0c_misc(const float* __restrict__ bx, const float* __restrict__ br,
                         int* __restrict__ qbx, int* __restrict__ qbr,
                         int* __restrict__ lut, u32* __restrict__ ring){
  int i = blockIdx.x * 256 + threadIdx.x;         // 4096 threads
  if (i < 1536) {
    qbx[i] = iclip8((int)rintf(bx[i] * 256.f));
    qbr[i] = iclip8((int)rintf(br[i] * 256.f));
  }
  if (i < 256) {
    double v = (i - 128) * 0.125;                 // all possible pre-activations
    float sg = (float)(1.0 / (1.0 + exp(-v)));
    int qs = (int)rintf(sg * 256.f);
    lut[i] = qs < 0 ? 0 : (qs > 255 ? 255 : qs);
    float th = (float)tanh(v);
    lut[256 + i] = iclip8((int)rintf(th * 128.f));
  }
  // zero the ring EVERY launch via LLC stores: tags >=1, so no leftover matches
  llc_zero16(ring + i*8);
  llc_zero16(ring + i*8 + 4);
}

// ---------------- phase 1: Wx = fq(xq @ Wq, 4), stored int8 ----------------
// 128x128 tile, BK=64, int8 MFMA; 4 waves each a 64x64 quadrant of 4x4 tiles.
__global__ __launch_bounds__(256) void k1_gemm_wx(const i8* __restrict__ qx8,
                                                  const i8* __restrict__ qwT8,
                                                  i8* __restrict__ qwx){
  __shared__ i8 xs[128][80];
  __shared__ i8 ws[128][80];
  int bid = blockIdx.x;
  int n0 = (bid % 12) * 128;
  int m0 = (bid / 12) * 128;
  int tid = threadIdx.x;
  int lane = tid & 63, wid = tid >> 6;
  int wm = wid >> 1, wn = wid & 1;
  int g = lane >> 4, l15 = lane & 15;

  i32x4 acc[4][4] = {};
  for (int kc = 0; kc < 512; kc += 64) {
    __syncthreads();
#pragma unroll
    for (int p = 0; p < 4; p++) {
      int idx = p*256 + tid;
      int mat = idx >> 9;
      int i2  = idx & 511;
      int r   = i2 >> 2;
      int c16 = (i2 & 3) << 4;
      const i8* src = mat ? qwT8 : qx8;
      int base = mat ? n0 : m0;
      uint4 val = *(const uint4*)&src[(size_t)(base + r)*512 + kc + c16];
      if (mat) *(uint4*)&ws[r][c16] = val;
      else     *(uint4*)&xs[r][c16] = val;
    }
    __syncthreads();
    i32x4 a[4], b[4];
#pragma unroll
    for (int t = 0; t < 4; t++) {
      a[t] = *(const i32x4*)&xs[wm*64 + t*16 + l15][g*16];
      b[t] = *(const i32x4*)&ws[wn*64 + t*16 + l15][g*16];
    }
#pragma unroll
    for (int i = 0; i < 4; i++)
#pragma unroll
      for (int j = 0; j < 4; j++)
        acc[i][j] = mfma_i8(a[i], b[j], acc[i][j]);
  }
#pragma unroll
  for (int i = 0; i < 4; i++)
#pragma unroll
    for (int j = 0; j < 4; j++)
#pragma unroll
      for (int r = 0; r < 4; r++) {
        int q = iclip8(rhe(acc[i][j][r], 10));
        int row = m0 + wm*64 + i*16 + g*4 + r;
        int col = n0 + wn*64 + j*16 + l15;
        qwx[(size_t)row * 1536 + col] = (i8)q;
      }
}

// ---------------- phase 2: 512-step recurrence ----------------
// 64 WGs (R2 decomposition): bg owns 16 batch rows, cg owns 32 h-cols (96 Rh
// cols); wave = K-slice of 128 (each wave depends on only ~4 producers).
// h exchanged via the PROVEN single LLC ring (sc0 sc1 both sides), tagged
// int8-pair words, fence-free. Body: i8 MFMA + perm-pack + fused i32
// reduce+gates, ONE barrier per step (parity LDS buffer).
__global__ __launch_bounds__(256, 1) void k2_gru(const float* __restrict__ h0,
                                                 const i8*  __restrict__ qwx,
                                                 const i8*  __restrict__ qrT8,
                                                 const int* __restrict__ qbx,
                                                 const int* __restrict__ qbr,
                                                 const int* __restrict__ lut,
                                                 u32* __restrict__ ring,
                                                 float* __restrict__ out){
  const int bid = blockIdx.x;
  const int bg  = (bid & 7) >> 1;                 // R2's XCD-spreading mapping
  const int cg  = ((bid >> 3) << 1) | (bid & 1);  // 0..15
  const int tid = threadIdx.x;
  const int lane = tid & 63, wid = tid >> 6;      // wave = K-slice of 128
  const int g = lane >> 4, l15 = lane & 15;

  __shared__ int l_sig[256], l_th[256];
  __shared__ int red[2][4][16][100];              // [parity][wave][row][96+pad]

  l_sig[tid] = lut[tid];
  l_th[tid]  = lut[256 + tid];

  // ---- R fragments (B operand), int8, resident: 6 n-tiles x 2 k-chunks
  i32x4 rf[6][2];
#pragma unroll
  for (int n = 0; n < 6; n++) {
    int colR = (n >> 1)*512 + cg*32 + (n & 1)*16 + l15;   // B: col = lane&15
#pragma unroll
    for (int m = 0; m < 2; m++)
      rf[n][m] = *(const i32x4*)&qrT8[(size_t)colR*512 + wid*128 + m*64 + g*16];
  }

  // ---- own h state: 2 elements per thread (row = tid>>4, cols c0,c0+1)
  const int row = tid >> 4;
  const int c0  = (tid & 15) << 1;
  int bxz[2], bxr[2], bxn[2], brz[2], brr[2], brn[2];
#pragma unroll
  for (int cc = 0; cc < 2; cc++) {
    int col = cg*32 + c0 + cc;
    bxz[cc] = qbx[col]; bxr[cc] = qbx[512 + col]; bxn[cc] = qbx[1024 + col];
    brz[cc] = qbr[col]; brr[cc] = qbr[512 + col]; brn[cc] = qbr[1024 + col];
  }
  int qh[2];
  {
    float2 h2 = *(const float2*)&h0[(size_t)(bg*16 + row)*512 + cg*32 + c0];
    qh[0] = qi8(h2.x, 128.f); qh[1] = qi8(h2.y, 128.f);
  }

  // producer word index (R4-proven layout): k = cg*32+c0, word = 2 int8 + tag16
  const int kprod = cg*32 + c0;
  const int pwidx = ((((kprod >> 7)*4 + ((kprod >> 4) & 3))*16 + row)*16)
                  + (((kprod >> 6) & 1) << 3) + ((kprod >> 1) & 7);

  const u64 ringb = (u64)ring;

  // ---- publish h(0): slot 0, tag 1
  {
    u32 wv = (u32)(qh[0] & 0xFF) | ((u32)(qh[1] & 0xFF) << 8) | (1u << 16);
    st_llc((u32*)(ringb + (u64)(bg*16384 + pwidx*4)), wv);
  }

  // ---- Wx pre-load for t=0 (one step ahead thereafter)
  u32 wzw, wrw, wgw;
  {
    const i8* wxp = qwx + (size_t)(bg*16 + row)*1536 + cg*32;
    wzw = *(const u16*)(wxp + c0);
    wrw = *(const u16*)(wxp + 512 + c0);
    wgw = *(const u16*)(wxp + 1024 + c0);
  }

  // consumer poll base: lane reads 64B covering its 32 k-values (16 words)
  const u64 laneoff = (u64)((wid*64 + g*16 + l15) * 64);

  for (int t = 0; t < NSTEP; t++) {
    const u32 want2 = (u32)(t + 1) | ((u32)(t + 1) << 16);
    const u64 aP = ringb + (u64)(((t & 1)*4 + bg) * 16384) + laneoff;
    uint4 P0, P1, P2, P3;
    int rounds = 0;
    for (;;) {
      asm volatile(
        "global_load_dwordx4 %0, %4, off sc0 sc1\n\t"
        "global_load_dwordx4 %1, %4, off offset:16 sc0 sc1\n\t"
        "global_load_dwordx4 %2, %4, off offset:32 sc0 sc1\n\t"
        "global_load_dwordx4 %3, %4, off offset:48 sc0 sc1\n\t"
        "s_waitcnt vmcnt(0)"
        : "=&v"(P0), "=&v"(P1), "=&v"(P2), "=&v"(P3) : "v"(aP) : "memory");
      u32 diff;
      diff  = __builtin_amdgcn_perm(P0.y, P0.x, 0x07060302u) ^ want2;
      diff |= __builtin_amdgcn_perm(P0.w, P0.z, 0x07060302u) ^ want2;
      diff |= __builtin_amdgcn_perm(P1.y, P1.x, 0x07060302u) ^ want2;
      diff |= __builtin_amdgcn_perm(P1.w, P1.z, 0x07060302u) ^ want2;
      diff |= __builtin_amdgcn_perm(P2.y, P2.x, 0x07060302u) ^ want2;
      diff |= __builtin_amdgcn_perm(P2.w, P2.z, 0x07060302u) ^ want2;
      diff |= __builtin_amdgcn_perm(P3.y, P3.x, 0x07060302u) ^ want2;
      diff |= __builtin_amdgcn_perm(P3.w, P3.z, 0x07060302u) ^ want2;
      if (diff == 0u) break;
      if (++rounds > (1 << 22)) break;            // hang-prevention only
      __builtin_amdgcn_s_sleep(1);
    }

    // next-step Wx prefetch (latency hides under compute + next poll)
    u32 nzw = 0, nrw = 0, ngw = 0;
    if (t < NSTEP - 1) {
      const i8* wxp = qwx + (size_t)(t + 1)*98304 + (size_t)(bg*16 + row)*1536 + cg*32;
      nzw = *(const u16*)(wxp + c0);
      nrw = *(const u16*)(wxp + 512 + c0);
      ngw = *(const u16*)(wxp + 1024 + c0);
    }

    // ---- pack A (strip tags) and run the 12 MFMAs
    i32x4 acc[6] = {};
    {
      i32x4 a0, a1;
      a0.x = (int)__builtin_amdgcn_perm(P0.y, P0.x, 0x05040100u);
      a0.y = (int)__builtin_amdgcn_perm(P0.w, P0.z, 0x05040100u);
      a0.z = (int)__builtin_amdgcn_perm(P1.y, P1.x, 0x05040100u);
      a0.w = (int)__builtin_amdgcn_perm(P1.w, P1.z, 0x05040100u);
      a1.x = (int)__builtin_amdgcn_perm(P2.y, P2.x, 0x05040100u);
      a1.y = (int)__builtin_amdgcn_perm(P2.w, P2.z, 0x05040100u);
      a1.z = (int)__builtin_amdgcn_perm(P3.y, P3.x, 0x05040100u);
      a1.w = (int)__builtin_amdgcn_perm(P3.w, P3.z, 0x05040100u);
#pragma unroll
      for (int n = 0; n < 6; n++) acc[n] = mfma_i8(a0, rf[n][0], acc[n]);
#pragma unroll
      for (int n = 0; n < 6; n++) acc[n] = mfma_i8(a1, rf[n][1], acc[n]);
    }

    // ---- per-wave partials to LDS (parity buffer), ONE barrier per step
    const int par = t & 1;
#pragma unroll
    for (int n = 0; n < 6; n++)
#pragma unroll
      for (int r = 0; r < 4; r++)
        red[par][wid][g*4 + r][n*16 + l15] = acc[n][r];
    __syncthreads();

    // ---- fused reduce + quantize + gates for this thread's 2 columns
    const int* rbase = &red[par][0][row][0];      // wave stride = 1600 ints
    int rz[2], rr[2], rg[2];
#pragma unroll
    for (int cc = 0; cc < 2; cc++) {
      int c = c0 + cc;
      int Sz = rbase[c]      + rbase[1600 + c]    + rbase[3200 + c]    + rbase[4800 + c];
      int Sr = rbase[32 + c] + rbase[1632 + c]    + rbase[3232 + c]    + rbase[4832 + c];
      int Sn = rbase[64 + c] + rbase[1664 + c]    + rbase[3264 + c]    + rbase[4864 + c];
      rz[cc] = iclip8(rhe(iclip8(rhe(Sz, 13))*16 + brz[cc], 4));
      rr[cc] = iclip8(rhe(iclip8(rhe(Sr, 13))*16 + brr[cc], 4));
      rg[cc] = iclip8(rhe(iclip8(rhe(Sn, 13))*16 + brn[cc], 4));
    }
#pragma unroll
    for (int cc = 0; cc < 2; cc++) {
      int wz = (int)(i8)((wzw >> (8*cc)) & 0xFF);
      int wr = (int)(i8)((wrw >> (8*cc)) & 0xFF);
      int wg = (int)(i8)((wgw >> (8*cc)) & 0xFF);
      int uz  = l_sig[128 + iclip8(rhe(16*(wz + rz[cc]) + bxz[cc], 5))];
      int ur  = l_sig[128 + iclip8(rhe(16*(wr + rr[cc]) + bxr[cc], 5))];
      int qrh = iclip8(rhe(ur * rg[cc], 8));
      int qg  = l_th[128 + iclip8(rhe(16*(wg + qrh) + bxn[cc], 5))];
      int qold = iclip8(rhe(uz * qh[cc], 8));
      int qnew = iclip8(rhe((256 - uz) * qg, 8));
      qh[cc] = iclip8(qold + qnew);
    }

    // ---- publish h(t+1) FIRST (earliest cross-WG visibility), then out
    {
      u32 tg = (u32)(t + 2) << 16;
      u32 wv = (u32)(qh[0] & 0xFF) | ((u32)(qh[1] & 0xFF) << 8) | tg;
      st_llc((u32*)(ringb + (u64)((((t + 1) & 1)*4 + bg)*16384 + pwidx*4)), wv);
    }
    float2 ov;
    ov.x = qh[0] * 0.0078125f; ov.y = qh[1] * 0.0078125f;
    *(float2*)&out[((size_t)t*64 + bg*16 + row)*512 + cg*32 + c0] = ov;

    wzw = nzw; wrw = nrw; wgw = ngw;
  }
}

// ---------------- launch ----------------
extern "C" void kernel_launch(void* const* d_in, const int* in_sizes, int n_in,
                              void* d_out, int out_size, void* d_ws, size_t ws_size,
                              hipStream_t stream) {
  const float* x  = (const float*)d_in[0];
  const float* h0 = (const float*)d_in[1];
  const float* W  = (const float*)d_in[2];
  const float* R  = (const float*)d_in[3];
  const float* bx = (const float*)d_in[4];
  const float* br = (const float*)d_in[5];
  float* out = (float*)d_out;

  if (ws_size < WS_NEED) return;   // insufficient scratch; fail loudly

  char* ws = (char*)d_ws;
  i8*  qx8   = (i8*) (ws + OFF_QX8);
  i8*  qwT8  = (i8*) (ws + OFF_QWT8);
  i8*  qrT8  = (i8*) (ws + OFF_QRT8);
  i8*  qwx   = (i8*) (ws + OFF_QWX);
  int* qbx   = (int*)(ws + OFF_QBX);
  int* qbr   = (int*)(ws + OFF_QBR);
  int* lut   = (int*)(ws + OFF_LUT);
  u32* ring  = (u32*)(ws + OFF_RING);

  k0a_qx  <<<2048, 256, 0, stream>>>(x, (u32*)qx8, 32768*512/4);
  k0b_qwr <<<6144, 256, 0, stream>>>(W, R, qwT8, qrT8);
  k0c_misc<<<16,   256, 0, stream>>>(bx, br, qbx, qbr, lut, ring);
  k1_gemm_wx<<<3072, 256, 0, stream>>>(qx8, qwT8, qwx);
  k2_gru  <<<64, 256, 0, stream>>>(h0, qwx, qrT8, qbx, qbr, lut, ring, out);
}